// Round 12
// baseline (156.860 us; speedup 1.0000x reference)
//
#include <hip/hip_runtime.h>
#include <hip/hip_bf16.h>

#define LL 64
#define HH 64
#define KDIM 4096   // L*H

typedef __attribute__((ext_vector_type(8))) short bf16x8;
typedef __attribute__((ext_vector_type(4))) short s16x4;
typedef __attribute__((ext_vector_type(4))) float f32x4;
typedef __attribute__((ext_vector_type(16))) float f32x16;

__device__ inline short f2bf(float f) {
    __hip_bfloat16 h = __float2bfloat16(f);
    return *reinterpret_cast<short*>(&h);
}
__device__ inline float elu1(float x) { return x > 0.f ? x : expm1f(x); }

__device__ inline void global_load_lds16(const short* g, short* l) {
    __builtin_amdgcn_global_load_lds(
        (const __attribute__((address_space(1))) unsigned int*)g,
        (__attribute__((address_space(3))) unsigned int*)l,
        16, 0, 0);
}

// ---------- fused prep: transpose+cvt W1 (tri-skip), W2, W0 + one-hot ----------
__global__ __launch_bounds__(256) void k_prep_all(
    const float* __restrict__ W1, short* __restrict__ W1T,
    const float* __restrict__ W2, short* __restrict__ W2T,
    const float* __restrict__ W0, short* __restrict__ W0T,
    const int* __restrict__ x, short* __restrict__ Xoh)
{
    int bid = blockIdx.x;
    if (bid >= 18432) {                               // one-hot of shifted x
        int id = bid - 18432;
        int b = id * 4 + (threadIdx.x >> 6);
        int t = threadIdx.x & 63;
        s16x4 v = {0, 0, 0, 0};
        if (t > 0) {
            int xi = x[b * LL + t - 1];
            v[xi] = (short)0x3F80;                    // bf16 1.0
        }
        *(s16x4*)(Xoh + (size_t)b * 256 + t * 4) = v;
        return;
    }
    const float* in; short* out; int R, C, bx, by;
    if (bid < 16384) {
        bx = bid & 127; by = bid >> 7;
        if (by * 32 >= bx * 32 + 160) return;         // triangular skip (margin 160:
        in = W1; out = W1T; R = 4096; C = 4096;       // GEMM reads k<n0+128 incl. zeros)
    } else if (bid < 17408) {
        int id = bid - 16384; bx = id & 7; by = id >> 3;
        in = W2; out = W2T; R = 4096; C = 256;
    } else {
        int id = bid - 17408; bx = id & 127; by = id >> 7;
        in = W0; out = W0T; R = 256; C = 4096;
    }
    __shared__ float tile[32][33];
    int tx = threadIdx.x & 31, ty = threadIdx.x >> 5;
    size_t r0 = (size_t)by * 32, c0 = (size_t)bx * 32;
#pragma unroll
    for (int i = 0; i < 32; i += 8)
        tile[ty + i][tx] = in[(r0 + ty + i) * C + (c0 + tx)];
    __syncthreads();
#pragma unroll
    for (int i = 0; i < 32; i += 8)
        out[(c0 + ty + i) * R + (r0 + tx)] = f2bf(tile[tx][ty + i]);
}

// ======== BK=64 swizzled-LDS, counted-vmcnt pipe, 32x32x16 MFMA ========
// LDS [128][64] bf16 x2 buffers; 16B slot s of row r holds global slot (s-r)&7.
// Per K-tile: 16 ds_read_b128 + 16 mfma_32x32x16 (was 32 mfma_16x16x32 —
// same FLOPs, half the issue slots, +15% ubench rate, identical bank pattern).
// Fragments: A/B lane l holds 8 k-contig elems (row=l&31, k=(l>>5)*8+j);
// C/D col=lane&31, row=(reg&3)+8*(reg>>2)+4*(lane>>5)  [guide m74/m101].
template<int SHIFT, bool OUT_BF16>
__global__ __launch_bounds__(256) void k_gemm_bt64_pipe(
    const short* __restrict__ A, const short* __restrict__ BT,
    const float* __restrict__ bias, void* __restrict__ Cv,
    int M, int N, int K)
{
    constexpr int BM = 128, BN = 128, BK = 64;
    constexpr int BUF = BM * BK;
    __shared__ short As[2 * BUF];
    __shared__ short Bs[2 * BUF];

    int m0 = blockIdx.x * BM;
    int n0 = ((int)gridDim.y - 1 - (int)blockIdx.y) * BN;   // heaviest-first
    int tid = threadIdx.x;
    int wave = tid >> 6, lane = tid & 63;
    int wm = (wave >> 1) * 64, wn = (wave & 1) * 64;

    int ke;
    if constexpr (SHIFT >= 0) ke = (n0 + BN) << SHIFT;
    else                      ke = (n0 + BN) >> (-SHIFT);
    int k_end = min(K, ke);
    int nt = (k_end + BK - 1) / BK;

    f32x16 acc[2][2] = {};

    // staging (unchanged): 4 calls/operand/wave; call c covers rows (wave*4+c)*8..+8
    const short* gA[4]; const short* gB[4];
    int lofs[4];
#pragma unroll
    for (int c = 0; c < 4; ++c) {
        int r  = (wave * 4 + c) * 8 + (lane >> 3);
        int gc = (((lane & 7) - r) & 7) * 8;        // inverse slot rotation
        gA[c] = A  + (size_t)(m0 + r) * K + gc;
        gB[c] = BT + (size_t)(n0 + r) * K + gc;
        lofs[c] = (wave * 4 + c) * 512;
    }

    // read offsets (elements), loop-invariant; slot = (ks*2 + khalf + row)&7
    int l31 = lane & 31, kh = lane >> 5;
    int offA[2][4], offB[2][4];
#pragma unroll
    for (int i = 0; i < 2; ++i) {
#pragma unroll
        for (int ks = 0; ks < 4; ++ks) {
            int ra = wm + i * 32 + l31;
            int rb = wn + i * 32 + l31;
            offA[i][ks] = ra * 64 + (((ks * 2 + kh) + ra) & 7) * 8;
            offB[i][ks] = rb * 64 + (((ks * 2 + kh) + rb) & 7) * 8;
        }
    }

    // prologue: issue tile 0's loads (no drain)
#pragma unroll
    for (int c = 0; c < 4; ++c) {
        global_load_lds16(gA[c], As + lofs[c]);
        global_load_lds16(gB[c], Bs + lofs[c]);
    }

    int cur = 0;
    for (int t = 0; t < nt; ++t) {
        if (t + 1 < nt) {                           // issue next tile's loads
            int kb = (t + 1) * BK;
            int bo = (cur ^ 1) * BUF;
#pragma unroll
            for (int c = 0; c < 4; ++c) {
                global_load_lds16(gA[c] + kb, As + bo + lofs[c]);
                global_load_lds16(gB[c] + kb, Bs + bo + lofs[c]);
            }
            asm volatile("s_waitcnt vmcnt(8)" ::: "memory");  // t done, t+1 in flight
        } else {
            asm volatile("s_waitcnt vmcnt(0)" ::: "memory");
        }
        __builtin_amdgcn_s_barrier();
        asm volatile("" ::: "memory");

        const short* bA = As + cur * BUF;
        const short* bB = Bs + cur * BUF;
        __builtin_amdgcn_s_setprio(1);
#pragma unroll
        for (int ks = 0; ks < 4; ++ks) {
            bf16x8 af[2], bfr[2];
#pragma unroll
            for (int i = 0; i < 2; ++i) {
                af[i]  = *(const bf16x8*)(bA + offA[i][ks]);
                bfr[i] = *(const bf16x8*)(bB + offB[i][ks]);
            }
#pragma unroll
            for (int mi = 0; mi < 2; ++mi)
#pragma unroll
                for (int ni = 0; ni < 2; ++ni)
                    acc[mi][ni] = __builtin_amdgcn_mfma_f32_32x32x16_bf16(
                        af[mi], bfr[ni], acc[mi][ni], 0, 0, 0);
        }
        __builtin_amdgcn_s_setprio(0);
        asm volatile("" ::: "memory");
        __builtin_amdgcn_s_barrier();
        asm volatile("" ::: "memory");
        cur ^= 1;
    }

    // epilogue: C/D layout col=lane&31, row=(rg&3)+8*(rg>>2)+4*(lane>>5)
    int rquad = (lane >> 5) * 4;
#pragma unroll
    for (int mi = 0; mi < 2; ++mi) {
#pragma unroll
        for (int ni = 0; ni < 2; ++ni) {
            int col = n0 + wn + ni * 32 + l31;
            float bv = bias[col];
#pragma unroll
            for (int rg = 0; rg < 16; ++rg) {
                int row = m0 + wm + mi * 32 + (rg & 3) + 8 * (rg >> 2) + rquad;
                float v = elu1(acc[mi][ni][rg] + bv);
                if (OUT_BF16) ((short*)Cv)[(size_t)row * N + col] = f2bf(v);
                else          ((float*)Cv)[(size_t)row * N + col] = v;
            }
        }
    }
}

// ---------- split-K partials (layer 3), same pipe + 32x32x16 core ----------
template<int SHIFT, int ZSPLIT>
__global__ __launch_bounds__(256) void k_gemm_bt64_splitk(
    const short* __restrict__ A, const short* __restrict__ BT,
    float* __restrict__ part, int M, int N, int K)
{
    constexpr int BM = 128, BN = 128, BK = 64;
    constexpr int BUF = BM * BK;
    __shared__ short As[2 * BUF];
    __shared__ short Bs[2 * BUF];

    int m0 = blockIdx.x * BM;
    int n0 = ((int)gridDim.y - 1 - (int)blockIdx.y) * BN;
    int z = blockIdx.z;
    int tid = threadIdx.x;
    int wave = tid >> 6, lane = tid & 63;
    int wm = (wave >> 1) * 64, wn = (wave & 1) * 64;

    int k_end = min(K, (n0 + BN) << SHIFT);
    int chunk = ((k_end / ZSPLIT + BK - 1) / BK) * BK;
    int kb0 = z * chunk;
    int kb1 = min(k_end, kb0 + chunk);
    int nt = (kb1 - kb0 + BK - 1) / BK;

    f32x16 acc[2][2] = {};

    const short* gA[4]; const short* gB[4];
    int lofs[4];
#pragma unroll
    for (int c = 0; c < 4; ++c) {
        int r  = (wave * 4 + c) * 8 + (lane >> 3);
        int gc = (((lane & 7) - r) & 7) * 8;
        gA[c] = A  + (size_t)(m0 + r) * K + gc + kb0;
        gB[c] = BT + (size_t)(n0 + r) * K + gc + kb0;
        lofs[c] = (wave * 4 + c) * 512;
    }

    int l31 = lane & 31, kh = lane >> 5;
    int offA[2][4], offB[2][4];
#pragma unroll
    for (int i = 0; i < 2; ++i) {
#pragma unroll
        for (int ks = 0; ks < 4; ++ks) {
            int ra = wm + i * 32 + l31;
            int rb = wn + i * 32 + l31;
            offA[i][ks] = ra * 64 + (((ks * 2 + kh) + ra) & 7) * 8;
            offB[i][ks] = rb * 64 + (((ks * 2 + kh) + rb) & 7) * 8;
        }
    }

    int rquad = (lane >> 5) * 4;

    if (nt <= 0) {
        float* p = part + (size_t)z * M * N;
#pragma unroll
        for (int mi = 0; mi < 2; ++mi)
#pragma unroll
            for (int ni = 0; ni < 2; ++ni)
#pragma unroll
                for (int rg = 0; rg < 16; ++rg) {
                    int row = m0 + wm + mi * 32 + (rg & 3) + 8 * (rg >> 2) + rquad;
                    int col = n0 + wn + ni * 32 + l31;
                    p[(size_t)row * N + col] = 0.f;
                }
        return;
    }

#pragma unroll
    for (int c = 0; c < 4; ++c) {
        global_load_lds16(gA[c], As + lofs[c]);
        global_load_lds16(gB[c], Bs + lofs[c]);
    }

    int cur = 0;
    for (int t = 0; t < nt; ++t) {
        if (t + 1 < nt) {
            int kb = (t + 1) * BK;
            int bo = (cur ^ 1) * BUF;
#pragma unroll
            for (int c = 0; c < 4; ++c) {
                global_load_lds16(gA[c] + kb, As + bo + lofs[c]);
                global_load_lds16(gB[c] + kb, Bs + bo + lofs[c]);
            }
            asm volatile("s_waitcnt vmcnt(8)" ::: "memory");
        } else {
            asm volatile("s_waitcnt vmcnt(0)" ::: "memory");
        }
        __builtin_amdgcn_s_barrier();
        asm volatile("" ::: "memory");

        const short* bA = As + cur * BUF;
        const short* bB = Bs + cur * BUF;
        __builtin_amdgcn_s_setprio(1);
#pragma unroll
        for (int ks = 0; ks < 4; ++ks) {
            bf16x8 af[2], bfr[2];
#pragma unroll
            for (int i = 0; i < 2; ++i) {
                af[i]  = *(const bf16x8*)(bA + offA[i][ks]);
                bfr[i] = *(const bf16x8*)(bB + offB[i][ks]);
            }
#pragma unroll
            for (int mi = 0; mi < 2; ++mi)
#pragma unroll
                for (int ni = 0; ni < 2; ++ni)
                    acc[mi][ni] = __builtin_amdgcn_mfma_f32_32x32x16_bf16(
                        af[mi], bfr[ni], acc[mi][ni], 0, 0, 0);
        }
        __builtin_amdgcn_s_setprio(0);
        asm volatile("" ::: "memory");
        __builtin_amdgcn_s_barrier();
        asm volatile("" ::: "memory");
        cur ^= 1;
    }

    float* p = part + (size_t)z * M * N;
#pragma unroll
    for (int mi = 0; mi < 2; ++mi)
#pragma unroll
        for (int ni = 0; ni < 2; ++ni) {
            int col = n0 + wn + ni * 32 + l31;
#pragma unroll
            for (int rg = 0; rg < 16; ++rg) {
                int row = m0 + wm + mi * 32 + (rg & 3) + 8 * (rg >> 2) + rquad;
                p[(size_t)row * N + col] = acc[mi][ni][rg];
            }
        }
}

// ---------- fused: reduce 8 split-K partials + bias + elu + log-softmax + gather ----------
__global__ __launch_bounds__(256) void k_logp_fused(
    const float* __restrict__ part, const float* __restrict__ b2,
    const int* __restrict__ x, float* __restrict__ logp)
{
    const size_t MN = (size_t)4096 * 256;
    int b = blockIdx.x * 4 + (threadIdx.x >> 6);
    int j = threadIdx.x & 63;
    size_t idx = (size_t)b * 256 + j * 4;

    f32x4 o = *(const f32x4*)(part + idx);
#pragma unroll
    for (int z = 1; z < 8; ++z) {
        f32x4 p = *(const f32x4*)(part + idx + (size_t)z * MN);
#pragma unroll
        for (int s = 0; s < 4; ++s) o[s] += p[s];
    }
    f32x4 bv = *(const f32x4*)(b2 + j * 4);
#pragma unroll
    for (int s = 0; s < 4; ++s)
        o[s] = elu1(o[s] + bv[s]);

    float m = fmaxf(fmaxf(o[0], o[1]), fmaxf(o[2], o[3]));
    float lse = m + logf(expf(o[0] - m) + expf(o[1] - m) +
                         expf(o[2] - m) + expf(o[3] - m));
    int xi = x[b * LL + j];
    float sel = (xi == 0) ? o[0] : (xi == 1) ? o[1] : (xi == 2) ? o[2] : o[3];
    float c = sel - lse;
#pragma unroll
    for (int off = 32; off > 0; off >>= 1)
        c += __shfl_down(c, off, 64);
    if (j == 0) logp[b] = c;
}

extern "C" void kernel_launch(void* const* d_in, const int* in_sizes, int n_in,
                              void* d_out, int out_size, void* d_ws, size_t ws_size,
                              hipStream_t stream)
{
    const int*   x  = (const int*)  d_in[0];
    const float* W0 = (const float*)d_in[1];
    const float* W1 = (const float*)d_in[2];
    const float* W2 = (const float*)d_in[3];
    const float* b0 = (const float*)d_in[4];
    const float* b1 = (const float*)d_in[5];
    const float* b2 = (const float*)d_in[6];
    float* logp = (float*)d_out;

    char* ws = (char*)d_ws;
    short* W1T  = (short*)(ws);                        // 4096x4096 bf16 = 32 MiB
    short* W2T  = (short*)(ws + (size_t)33554432);     //  256x4096 bf16 =  2 MiB
    short* W0T  = (short*)(ws + (size_t)35651584);     // 4096x256  bf16 =  2 MiB
    short* Xoh  = (short*)(ws + (size_t)37748736);     // 4096x256  bf16 =  2 MiB
    short* A1   = (short*)(ws + (size_t)39845888);     // 4096x4096 bf16 = 32 MiB
    float* part = (float*)(ws + (size_t)39845888);     // aliases A1: 8 x 4 MiB = 32 MiB
    short* A2   = (short*)(ws + (size_t)73400320);     // 4096x4096 bf16 = 32 MiB

    // fused weight prep + one-hot (one launch)
    k_prep_all<<<19456, 256, 0, stream>>>(W1, W1T, W2, W2T, W0, W0T, x, Xoh);

    // layer 1: A1 = elu(Xoh @ W0flat + b0)   [M=4096,N=4096,K=256]
    k_gemm_bt64_pipe<-4, true><<<dim3(32, 32), 256, 0, stream>>>(Xoh, W0T, b0, A1, 4096, 4096, 256);

    // layer 2: A2 = elu(A1 @ W1flat + b1)    [pipe, 32x32x16 MFMA]
    k_gemm_bt64_pipe<0, true><<<dim3(32, 32), 256, 0, stream>>>(A1, W1T, b1, A2, 4096, 4096, 4096);

    // layer 3: split-K partials               [M=4096,N=256, Z=8]
    k_gemm_bt64_splitk<4, 8><<<dim3(32, 2, 8), 256, 0, stream>>>(A2, W2T, part, 4096, 256, 4096);

    // fused reduce + bias + elu + logp
    k_logp_fused<<<1024, 256, 0, stream>>>(part, b2, x, logp);
}

// Round 13
// 146.894 us; speedup vs baseline: 1.0678x; 1.0678x over previous
//
#include <hip/hip_runtime.h>
#include <hip/hip_bf16.h>

#define LL 64
#define HH 64
#define KDIM 4096   // L*H

typedef __attribute__((ext_vector_type(8))) short bf16x8;
typedef __attribute__((ext_vector_type(4))) short s16x4;
typedef __attribute__((ext_vector_type(4))) float f32x4;

__device__ inline short f2bf(float f) {
    __hip_bfloat16 h = __float2bfloat16(f);
    return *reinterpret_cast<short*>(&h);
}
__device__ inline float elu1(float x) { return x > 0.f ? x : expm1f(x); }

__device__ inline void global_load_lds16(const short* g, short* l) {
    __builtin_amdgcn_global_load_lds(
        (const __attribute__((address_space(1))) unsigned int*)g,
        (__attribute__((address_space(3))) unsigned int*)l,
        16, 0, 0);
}

// ---------- fused prep: transpose+cvt W1 (tri-skip), W2, W0 + one-hot ----------
__global__ __launch_bounds__(256) void k_prep_all(
    const float* __restrict__ W1, short* __restrict__ W1T,
    const float* __restrict__ W2, short* __restrict__ W2T,
    const float* __restrict__ W0, short* __restrict__ W0T,
    const int* __restrict__ x, short* __restrict__ Xoh)
{
    int bid = blockIdx.x;
    if (bid >= 18432) {                               // one-hot of shifted x
        int id = bid - 18432;
        int b = id * 4 + (threadIdx.x >> 6);
        int t = threadIdx.x & 63;
        s16x4 v = {0, 0, 0, 0};
        if (t > 0) {
            int xi = x[b * LL + t - 1];
            v[xi] = (short)0x3F80;                    // bf16 1.0
        }
        *(s16x4*)(Xoh + (size_t)b * 256 + t * 4) = v;
        return;
    }
    const float* in; short* out; int R, C, bx, by;
    if (bid < 16384) {
        bx = bid & 127; by = bid >> 7;
        if (by * 32 >= bx * 32 + 160) return;         // triangular skip (margin 160:
        in = W1; out = W1T; R = 4096; C = 4096;       // GEMM reads k<n0+128 incl. zeros)
    } else if (bid < 17408) {
        int id = bid - 16384; bx = id & 7; by = id >> 3;
        in = W2; out = W2T; R = 4096; C = 256;
    } else {
        int id = bid - 17408; bx = id & 127; by = id >> 7;
        in = W0; out = W0T; R = 256; C = 4096;
    }
    __shared__ float tile[32][33];
    int tx = threadIdx.x & 31, ty = threadIdx.x >> 5;
    size_t r0 = (size_t)by * 32, c0 = (size_t)bx * 32;
#pragma unroll
    for (int i = 0; i < 32; i += 8)
        tile[ty + i][tx] = in[(r0 + ty + i) * C + (c0 + tx)];
    __syncthreads();
#pragma unroll
    for (int i = 0; i < 32; i += 8)
        out[(c0 + ty + i) * R + (r0 + tx)] = f2bf(tile[tx][ty + i]);
}

// ======== BK=64 MFMA GEMM, swizzled LDS, counted-vmcnt 2-deep pipeline ========
// LDS [128][64] bf16 x2 buffers/operand; 16B slot s of row r holds slot (s-r)&7.
// Per iter: issue stage(t+1) -> s_waitcnt vmcnt(8) (t's 8 loads done; t+1's
// stay IN FLIGHT across the raw barrier - T4) -> s_barrier -> MFMA(t) ->
// s_barrier (protect buf reuse). Never vmcnt(0) in the main loop.
// 16x16x32 MFMA only: its 16-row ds_read pattern is the one this swizzle
// makes conflict-free (32x32's 32-row pattern conflicts - R12 falsified).
template<int SHIFT, bool OUT_BF16>
__global__ __launch_bounds__(256) void k_gemm_bt64_pipe(
    const short* __restrict__ A, const short* __restrict__ BT,
    const float* __restrict__ bias, void* __restrict__ Cv,
    int M, int N, int K)
{
    constexpr int BM = 128, BN = 128, BK = 64;
    constexpr int BUF = BM * BK;                // 8192 elems = 16 KB
    __shared__ short As[2 * BUF];
    __shared__ short Bs[2 * BUF];

    int m0 = blockIdx.x * BM;
    int n0 = ((int)gridDim.y - 1 - (int)blockIdx.y) * BN;   // heaviest-first
    int tid = threadIdx.x;
    int wave = tid >> 6, lane = tid & 63;
    int wm = (wave >> 1) * 64, wn = (wave & 1) * 64;

    int ke;
    if constexpr (SHIFT >= 0) ke = (n0 + BN) << SHIFT;
    else                      ke = (n0 + BN) >> (-SHIFT);
    int k_end = min(K, ke);
    int nt = (k_end + BK - 1) / BK;

    f32x4 acc[4][4] = {};

    // staging: 4 calls/operand/wave; call c covers rows (wave*4+c)*8..+8
    const short* gA[4]; const short* gB[4];
    int lofs[4];
#pragma unroll
    for (int c = 0; c < 4; ++c) {
        int r  = (wave * 4 + c) * 8 + (lane >> 3);
        int gc = (((lane & 7) - r) & 7) * 8;        // inverse slot rotation
        gA[c] = A  + (size_t)(m0 + r) * K + gc;
        gB[c] = BT + (size_t)(n0 + r) * K + gc;
        lofs[c] = (wave * 4 + c) * 512;             // wave-uniform LDS base
    }

    // read offsets (elements), loop-invariant; j = h*4+q
    int q = lane >> 4, lrow = lane & 15;
    int offA[4][2], offB[4][2];
#pragma unroll
    for (int i = 0; i < 4; ++i) {
#pragma unroll
        for (int h = 0; h < 2; ++h) {
            int ra = wm + i * 16 + lrow;
            int rb = wn + i * 16 + lrow;
            offA[i][h] = ra * 64 + ((h * 4 + q + ra) & 7) * 8;
            offB[i][h] = rb * 64 + ((h * 4 + q + rb) & 7) * 8;
        }
    }

    // prologue: issue tile 0's loads (no drain)
#pragma unroll
    for (int c = 0; c < 4; ++c) {
        global_load_lds16(gA[c], As + lofs[c]);
        global_load_lds16(gB[c], Bs + lofs[c]);
    }

    int cur = 0;
    for (int t = 0; t < nt; ++t) {
        if (t + 1 < nt) {                           // issue next tile's loads
            int kb = (t + 1) * BK;
            int bo = (cur ^ 1) * BUF;
#pragma unroll
            for (int c = 0; c < 4; ++c) {
                global_load_lds16(gA[c] + kb, As + bo + lofs[c]);
                global_load_lds16(gB[c] + kb, Bs + bo + lofs[c]);
            }
            asm volatile("s_waitcnt vmcnt(8)" ::: "memory");  // t done, t+1 in flight
        } else {
            asm volatile("s_waitcnt vmcnt(0)" ::: "memory");  // last tile
        }
        __builtin_amdgcn_s_barrier();               // all waves' t-loads landed
        asm volatile("" ::: "memory");

        const short* bA = As + cur * BUF;
        const short* bB = Bs + cur * BUF;
        __builtin_amdgcn_s_setprio(1);
#pragma unroll
        for (int h = 0; h < 2; ++h) {
            bf16x8 af[4], bfr[4];
#pragma unroll
            for (int i = 0; i < 4; ++i) {
                af[i]  = *(const bf16x8*)(bA + offA[i][h]);
                bfr[i] = *(const bf16x8*)(bB + offB[i][h]);
            }
#pragma unroll
            for (int mi = 0; mi < 4; ++mi)
#pragma unroll
                for (int ni = 0; ni < 4; ++ni)
                    acc[mi][ni] = __builtin_amdgcn_mfma_f32_16x16x32_bf16(
                        af[mi], bfr[ni], acc[mi][ni], 0, 0, 0);
        }
        __builtin_amdgcn_s_setprio(0);
        asm volatile("" ::: "memory");
        __builtin_amdgcn_s_barrier();               // done reading buf before reuse
        asm volatile("" ::: "memory");
        cur ^= 1;
    }

    int lcol = lane & 15;
    int lr4  = (lane >> 4) * 4;
#pragma unroll
    for (int mi = 0; mi < 4; ++mi) {
#pragma unroll
        for (int ni = 0; ni < 4; ++ni) {
            int col = n0 + wn + ni * 16 + lcol;
            float bv = bias[col];
#pragma unroll
            for (int r = 0; r < 4; ++r) {
                int row = m0 + wm + mi * 16 + lr4 + r;
                float v = elu1(acc[mi][ni][r] + bv);
                if (OUT_BF16) ((short*)Cv)[(size_t)row * N + col] = f2bf(v);
                else          ((float*)Cv)[(size_t)row * N + col] = v;
            }
        }
    }
}

// ---------- split-K partials (layer 3), same counted-vmcnt pipeline ----------
template<int SHIFT, int ZSPLIT>
__global__ __launch_bounds__(256) void k_gemm_bt64_splitk(
    const short* __restrict__ A, const short* __restrict__ BT,
    float* __restrict__ part, int M, int N, int K)
{
    constexpr int BM = 128, BN = 128, BK = 64;
    constexpr int BUF = BM * BK;
    __shared__ short As[2 * BUF];
    __shared__ short Bs[2 * BUF];

    int m0 = blockIdx.x * BM;
    int n0 = ((int)gridDim.y - 1 - (int)blockIdx.y) * BN;
    int z = blockIdx.z;
    int tid = threadIdx.x;
    int wave = tid >> 6, lane = tid & 63;
    int wm = (wave >> 1) * 64, wn = (wave & 1) * 64;

    int k_end = min(K, (n0 + BN) << SHIFT);
    int chunk = ((k_end / ZSPLIT + BK - 1) / BK) * BK;
    int kb0 = z * chunk;
    int kb1 = min(k_end, kb0 + chunk);
    int nt = (kb1 - kb0 + BK - 1) / BK;

    f32x4 acc[4][4] = {};

    const short* gA[4]; const short* gB[4];
    int lofs[4];
#pragma unroll
    for (int c = 0; c < 4; ++c) {
        int r  = (wave * 4 + c) * 8 + (lane >> 3);
        int gc = (((lane & 7) - r) & 7) * 8;
        gA[c] = A  + (size_t)(m0 + r) * K + gc + kb0;
        gB[c] = BT + (size_t)(n0 + r) * K + gc + kb0;
        lofs[c] = (wave * 4 + c) * 512;
    }

    int q = lane >> 4, lrow = lane & 15;
    int offA[4][2], offB[4][2];
#pragma unroll
    for (int i = 0; i < 4; ++i) {
#pragma unroll
        for (int h = 0; h < 2; ++h) {
            int ra = wm + i * 16 + lrow;
            int rb = wn + i * 16 + lrow;
            offA[i][h] = ra * 64 + ((h * 4 + q + ra) & 7) * 8;
            offB[i][h] = rb * 64 + ((h * 4 + q + rb) & 7) * 8;
        }
    }

    int lcol = lane & 15;
    int lr4  = (lane >> 4) * 4;

    if (nt <= 0) {
        float* p = part + (size_t)z * M * N;
#pragma unroll
        for (int mi = 0; mi < 4; ++mi)
#pragma unroll
            for (int ni = 0; ni < 4; ++ni)
#pragma unroll
                for (int r = 0; r < 4; ++r)
                    p[(size_t)(m0 + wm + mi * 16 + lr4 + r) * N
                      + (n0 + wn + ni * 16 + lcol)] = 0.f;
        return;
    }

#pragma unroll
    for (int c = 0; c < 4; ++c) {
        global_load_lds16(gA[c], As + lofs[c]);
        global_load_lds16(gB[c], Bs + lofs[c]);
    }

    int cur = 0;
    for (int t = 0; t < nt; ++t) {
        if (t + 1 < nt) {
            int kb = (t + 1) * BK;
            int bo = (cur ^ 1) * BUF;
#pragma unroll
            for (int c = 0; c < 4; ++c) {
                global_load_lds16(gA[c] + kb, As + bo + lofs[c]);
                global_load_lds16(gB[c] + kb, Bs + bo + lofs[c]);
            }
            asm volatile("s_waitcnt vmcnt(8)" ::: "memory");
        } else {
            asm volatile("s_waitcnt vmcnt(0)" ::: "memory");
        }
        __builtin_amdgcn_s_barrier();
        asm volatile("" ::: "memory");

        const short* bA = As + cur * BUF;
        const short* bB = Bs + cur * BUF;
        __builtin_amdgcn_s_setprio(1);
#pragma unroll
        for (int h = 0; h < 2; ++h) {
            bf16x8 af[4], bfr[4];
#pragma unroll
            for (int i = 0; i < 4; ++i) {
                af[i]  = *(const bf16x8*)(bA + offA[i][h]);
                bfr[i] = *(const bf16x8*)(bB + offB[i][h]);
            }
#pragma unroll
            for (int mi = 0; mi < 4; ++mi)
#pragma unroll
                for (int ni = 0; ni < 4; ++ni)
                    acc[mi][ni] = __builtin_amdgcn_mfma_f32_16x16x32_bf16(
                        af[mi], bfr[ni], acc[mi][ni], 0, 0, 0);
        }
        __builtin_amdgcn_s_setprio(0);
        asm volatile("" ::: "memory");
        __builtin_amdgcn_s_barrier();
        asm volatile("" ::: "memory");
        cur ^= 1;
    }

    float* p = part + (size_t)z * M * N;
#pragma unroll
    for (int mi = 0; mi < 4; ++mi)
#pragma unroll
        for (int ni = 0; ni < 4; ++ni) {
            int col = n0 + wn + ni * 16 + lcol;
#pragma unroll
            for (int r = 0; r < 4; ++r) {
                int row = m0 + wm + mi * 16 + lr4 + r;
                p[(size_t)row * N + col] = acc[mi][ni][r];
            }
        }
}

// ---------- fused: reduce 8 split-K partials + bias + elu + log-softmax + gather ----------
__global__ __launch_bounds__(256) void k_logp_fused(
    const float* __restrict__ part, const float* __restrict__ b2,
    const int* __restrict__ x, float* __restrict__ logp)
{
    const size_t MN = (size_t)4096 * 256;
    int b = blockIdx.x * 4 + (threadIdx.x >> 6);
    int j = threadIdx.x & 63;
    size_t idx = (size_t)b * 256 + j * 4;

    f32x4 o = *(const f32x4*)(part + idx);
#pragma unroll
    for (int z = 1; z < 8; ++z) {
        f32x4 p = *(const f32x4*)(part + idx + (size_t)z * MN);
#pragma unroll
        for (int s = 0; s < 4; ++s) o[s] += p[s];
    }
    f32x4 bv = *(const f32x4*)(b2 + j * 4);
#pragma unroll
    for (int s = 0; s < 4; ++s)
        o[s] = elu1(o[s] + bv[s]);

    float m = fmaxf(fmaxf(o[0], o[1]), fmaxf(o[2], o[3]));
    float lse = m + logf(expf(o[0] - m) + expf(o[1] - m) +
                         expf(o[2] - m) + expf(o[3] - m));
    int xi = x[b * LL + j];
    float sel = (xi == 0) ? o[0] : (xi == 1) ? o[1] : (xi == 2) ? o[2] : o[3];
    float c = sel - lse;
#pragma unroll
    for (int off = 32; off > 0; off >>= 1)
        c += __shfl_down(c, off, 64);
    if (j == 0) logp[b] = c;
}

extern "C" void kernel_launch(void* const* d_in, const int* in_sizes, int n_in,
                              void* d_out, int out_size, void* d_ws, size_t ws_size,
                              hipStream_t stream)
{
    const int*   x  = (const int*)  d_in[0];
    const float* W0 = (const float*)d_in[1];
    const float* W1 = (const float*)d_in[2];
    const float* W2 = (const float*)d_in[3];
    const float* b0 = (const float*)d_in[4];
    const float* b1 = (const float*)d_in[5];
    const float* b2 = (const float*)d_in[6];
    float* logp = (float*)d_out;

    char* ws = (char*)d_ws;
    short* W1T  = (short*)(ws);                        // 4096x4096 bf16 = 32 MiB
    short* W2T  = (short*)(ws + (size_t)33554432);     //  256x4096 bf16 =  2 MiB
    short* W0T  = (short*)(ws + (size_t)35651584);     // 4096x256  bf16 =  2 MiB
    short* Xoh  = (short*)(ws + (size_t)37748736);     // 4096x256  bf16 =  2 MiB
    short* A1   = (short*)(ws + (size_t)39845888);     // 4096x4096 bf16 = 32 MiB
    float* part = (float*)(ws + (size_t)39845888);     // aliases A1: 8 x 4 MiB = 32 MiB
    short* A2   = (short*)(ws + (size_t)73400320);     // 4096x4096 bf16 = 32 MiB

    // fused weight prep + one-hot (one launch)
    k_prep_all<<<19456, 256, 0, stream>>>(W1, W1T, W2, W2T, W0, W0T, x, Xoh);

    // layer 1: A1 = elu(Xoh @ W0flat + b0)   [M=4096,N=4096,K=256]
    k_gemm_bt64_pipe<-4, true><<<dim3(32, 32), 256, 0, stream>>>(Xoh, W0T, b0, A1, 4096, 4096, 256);

    // layer 2: A2 = elu(A1 @ W1flat + b1)    [counted-vmcnt 2-deep pipeline]
    k_gemm_bt64_pipe<0, true><<<dim3(32, 32), 256, 0, stream>>>(A1, W1T, b1, A2, 4096, 4096, 4096);

    // layer 3: split-K partials               [M=4096,N=256, Z=8]
    k_gemm_bt64_splitk<4, 8><<<dim3(32, 2, 8), 256, 0, stream>>>(A2, W2T, part, 4096, 256, 4096);

    // fused reduce + bias + elu + logp
    k_logp_fused<<<1024, 256, 0, stream>>>(part, b2, x, logp);
}